// Round 1
// baseline (63.228 us; speedup 1.0000x reference)
//
#include <hip/hip_runtime.h>

// MidMaxPooling2D: x [16,256,256,64] f32, pool 2x2 stride 2 -> [16,128,128,64]
// out = 0.5*max(window) + 0.5*max(second_smallest(window), 0)

#define B_  16
#define H_  256
#define W_  256
#define C_  64

__device__ __forceinline__ float midmax1(float a, float b, float c, float d) {
    float lo1 = fminf(a, b), hi1 = fmaxf(a, b);
    float lo2 = fminf(c, d), hi2 = fmaxf(c, d);
    float mx  = fmaxf(hi1, hi2);
    // second smallest of 4 = min(max(lo1,lo2), min(hi1,hi2))
    float ss  = fminf(fmaxf(lo1, lo2), fminf(hi1, hi2));
    float mid = fmaxf(ss, 0.0f);
    return 0.5f * (mx + mid);   // ALPHA = 0.5
}

__global__ __launch_bounds__(256) void midmax_kernel(
        const float4* __restrict__ x, float4* __restrict__ out, int n_out4) {
    int idx = blockIdx.x * blockDim.x + threadIdx.x;
    if (idx >= n_out4) return;

    // idx = ((b*Ho + ho)*Wo + wo)*CV + cv   with Ho=Wo=128, CV=C/4=16
    int cv = idx & 15;
    int t  = idx >> 4;
    int wo = t & 127;
    t >>= 7;
    int ho = t & 127;
    int b  = t >> 7;

    // input strides in float4 units: cv:1, w:16, h:W_*16=4096, b:H_*W_*16=1048576
    long base = (long)b * (H_ * W_ * (C_ / 4))
              + (long)(2 * ho) * (W_ * (C_ / 4))
              + (2 * wo) * (C_ / 4)
              + cv;

    float4 v00 = x[base];
    float4 v01 = x[base + (C_ / 4)];
    float4 v10 = x[base + W_ * (C_ / 4)];
    float4 v11 = x[base + W_ * (C_ / 4) + (C_ / 4)];

    float4 r;
    r.x = midmax1(v00.x, v01.x, v10.x, v11.x);
    r.y = midmax1(v00.y, v01.y, v10.y, v11.y);
    r.z = midmax1(v00.z, v01.z, v10.z, v11.z);
    r.w = midmax1(v00.w, v01.w, v10.w, v11.w);

    out[idx] = r;
}

extern "C" void kernel_launch(void* const* d_in, const int* in_sizes, int n_in,
                              void* d_out, int out_size, void* d_ws, size_t ws_size,
                              hipStream_t stream) {
    const float4* x = (const float4*)d_in[0];
    float4* out = (float4*)d_out;
    int n_out4 = out_size / 4;   // 16*128*128*64/4 = 4,194,304
    int block = 256;
    int grid = (n_out4 + block - 1) / block;  // 16384
    midmax_kernel<<<grid, block, 0, stream>>>(x, out, n_out4);
}

// Round 3
// 59.435 us; speedup vs baseline: 1.0638x; 1.0638x over previous
//
#include <hip/hip_runtime.h>

// MidMaxPooling2D: x [16,256,256,64] f32, pool 2x2 stride 2 -> [16,128,128,64]
// out = 0.5*max(window) + 0.5*max(second_smallest(window), 0)
// R3: same as R2 but with ext_vector float4 so nontemporal builtins compile.

#define B_  16
#define H_  256
#define W_  256
#define C_  64
#define CV_ (C_ / 4)                        // 16 vec4 per pixel
#define IN_B_STRIDE  (H_ * W_ * CV_)        // 1,048,576 vec4
#define OUT_HALF     (8 * 128 * 128 * CV_)  // 2,097,152 vec4 (b = 0..7)

typedef float f32x4 __attribute__((ext_vector_type(4)));

__device__ __forceinline__ float midmax1(float a, float b, float c, float d) {
    float lo1 = fminf(a, b), hi1 = fmaxf(a, b);
    float lo2 = fminf(c, d), hi2 = fmaxf(c, d);
    float mx  = fmaxf(hi1, hi2);
    float ss  = fminf(fmaxf(lo1, lo2), fminf(hi1, hi2)); // 2nd smallest of 4
    float mid = fmaxf(ss, 0.0f);
    return 0.5f * (mx + mid);   // ALPHA = 0.5
}

__device__ __forceinline__ f32x4 midmax4(f32x4 a, f32x4 b, f32x4 c, f32x4 d) {
    f32x4 r;
    r.x = midmax1(a.x, b.x, c.x, d.x);
    r.y = midmax1(a.y, b.y, c.y, d.y);
    r.z = midmax1(a.z, b.z, c.z, d.z);
    r.w = midmax1(a.w, b.w, c.w, d.w);
    return r;
}

__global__ __launch_bounds__(256) void midmax_kernel(
        const f32x4* __restrict__ x, f32x4* __restrict__ out) {
    int idx = blockIdx.x * blockDim.x + threadIdx.x;   // 0 .. OUT_HALF-1

    // idx = ((b*Ho + ho)*Wo + wo)*CV + cv, Ho=Wo=128, CV=16, b in 0..7
    int cv = idx & 15;
    int t  = idx >> 4;
    int wo = t & 127;
    t >>= 7;
    int ho = t & 127;
    int b  = t >> 7;

    long base1 = (long)b * IN_B_STRIDE
               + (long)(2 * ho) * (W_ * CV_)
               + (2 * wo) * CV_
               + cv;
    long base2 = base1 + 8L * IN_B_STRIDE;

    // 8 loads issued back-to-back for MLP
    f32x4 a00 = __builtin_nontemporal_load(x + base1);
    f32x4 a01 = __builtin_nontemporal_load(x + base1 + CV_);
    f32x4 a10 = __builtin_nontemporal_load(x + base1 + W_ * CV_);
    f32x4 a11 = __builtin_nontemporal_load(x + base1 + W_ * CV_ + CV_);
    f32x4 b00 = __builtin_nontemporal_load(x + base2);
    f32x4 b01 = __builtin_nontemporal_load(x + base2 + CV_);
    f32x4 b10 = __builtin_nontemporal_load(x + base2 + W_ * CV_);
    f32x4 b11 = __builtin_nontemporal_load(x + base2 + W_ * CV_ + CV_);

    f32x4 r1 = midmax4(a00, a01, a10, a11);
    f32x4 r2 = midmax4(b00, b01, b10, b11);

    __builtin_nontemporal_store(r1, out + idx);
    __builtin_nontemporal_store(r2, out + idx + OUT_HALF);
}

extern "C" void kernel_launch(void* const* d_in, const int* in_sizes, int n_in,
                              void* d_out, int out_size, void* d_ws, size_t ws_size,
                              hipStream_t stream) {
    const f32x4* x = (const f32x4*)d_in[0];
    f32x4* out = (f32x4*)d_out;
    int block = 256;
    int grid = OUT_HALF / block;   // 8192
    midmax_kernel<<<grid, block, 0, stream>>>(x, out);
}